// Round 6
// baseline (8658.521 us; speedup 1.0000x reference)
//
#include <hip/hip_runtime.h>
#include <hip/hip_bf16.h>
#include <stdint.h>

// Sizes from the reference
#define BS   256
#define T_   128
#define TP   127      // T-1
#define DD   128
#define DT   16
#define DB   32
#define DH   256
#define NH   4
#define DS   64
#define DHN  1024

#define OFFV (256u*127u*64u)   // 2080768, size of each output tensor

typedef __attribute__((ext_vector_type(8))) short short8v;
typedef __attribute__((ext_vector_type(4))) float f32x4;
typedef __attribute__((ext_vector_type(2))) float f32x2;
typedef __attribute__((ext_vector_type(2))) unsigned int uint2v;

__device__ __forceinline__ float bf16lo(unsigned u){ return __uint_as_float(u << 16); }
__device__ __forceinline__ float bf16hi(unsigned u){ return __uint_as_float(u & 0xffff0000u); }
__device__ __forceinline__ unsigned short f2bf(float f){
  unsigned u = __float_as_uint(f);
  u += 0x7fffu + ((u >> 16) & 1u);   // RNE
  return (unsigned short)(u >> 16);
}
__device__ __forceinline__ unsigned pk2(float lo, float hi){
  return (unsigned)f2bf(lo) | ((unsigned)f2bf(hi) << 16);
}
__device__ __forceinline__ float softplus_f(float x){
  return fmaxf(x, 0.f) + log1pf(__expf(-fabsf(x)));
}

#define REP64(M) M(0) M(1) M(2) M(3) M(4) M(5) M(6) M(7) M(8) M(9) M(10) M(11) \
  M(12) M(13) M(14) M(15) M(16) M(17) M(18) M(19) M(20) M(21) M(22) M(23) \
  M(24) M(25) M(26) M(27) M(28) M(29) M(30) M(31) M(32) M(33) M(34) M(35) \
  M(36) M(37) M(38) M(39) M(40) M(41) M(42) M(43) M(44) M(45) M(46) M(47) \
  M(48) M(49) M(50) M(51) M(52) M(53) M(54) M(55) M(56) M(57) M(58) M(59) \
  M(60) M(61) M(62) M(63)

// ---------------------------------------------------------------------------
// Kernel 1: pack recurrent weights to bf16, paired along the reduction dim.
// ---------------------------------------------------------------------------
__global__ __launch_bounds__(256) void pack_w_kernel(
    const float* __restrict__ hk_w, const float* __restrict__ hv_w,
    const float* __restrict__ mut_w, const float* __restrict__ sgt_w,
    unsigned* __restrict__ hkp, unsigned* __restrict__ hvp,
    unsigned* __restrict__ mutp, unsigned* __restrict__ sgtp)
{
  int i = blockIdx.x * 256 + threadIdx.x;
  if (i < 32*256) { int s2 = i >> 8, d = i & 255;
    hkp[i] = pk2(hk_w[(2*s2)*256 + d], hk_w[(2*s2+1)*256 + d]); }
  if (i < 32*1024) { int s2 = i >> 10, j = i & 1023;
    hvp[i] = pk2(hv_w[(2*s2)*1024 + j], hv_w[(2*s2+1)*1024 + j]); }
  if (i < 512*64) { int J2 = i >> 6, k = i & 63;
    mutp[i] = pk2(mut_w[(2*J2)*64 + k], mut_w[(2*J2+1)*64 + k]);
    sgtp[i] = pk2(sgt_w[(2*J2)*64 + k], sgt_w[(2*J2+1)*64 + k]); }
}

// ---------------------------------------------------------------------------
// Kernel 2: projection GEMM (MFMA bf16 16x16x32).  One block per b.
// ---------------------------------------------------------------------------
#define LDA 168

__global__ __launch_bounds__(256) void proj_kernel(
    const float* __restrict__ x, const float* __restrict__ a,
    const float* __restrict__ q_w, const float* __restrict__ q_b,
    const float* __restrict__ v_w, const float* __restrict__ v_b,
    uint2v* __restrict__ Qp4, unsigned* __restrict__ Vws)
{
  const int b    = blockIdx.x;
  const int tid  = threadIdx.x;
  const int lane = tid & 63;
  const int w    = tid >> 6;

  __shared__ __align__(16) unsigned short A_s[128 * LDA];
  __shared__ __align__(16) unsigned short BC_s[64 * LDA];

  for (int idx = tid; idx < 128 * DD; idx += 256) {
    int t = idx >> 7, k = idx & 127;
    float v = (t < TP) ? x[((size_t)b * T_ + 1 + t) * DD + k] : 0.f;
    A_s[t * LDA + k] = f2bf(v);
  }
  for (int idx = tid; idx < 128 * 40; idx += 256) {
    int t = idx / 40, kk = idx % 40;
    float v = (t < TP && kk < DT) ? a[((size_t)b * T_ + t) * DT + kk] : 0.f;
    A_s[t * LDA + 128 + kk] = f2bf(v);
  }
  __syncthreads();

  for (int nt = 0; nt < 32; ++nt) {
    const int n0 = nt * 64;
    const bool isQ = (n0 < DHN);
    const float* wsrc = isQ ? q_w : v_w;
    const float* bias = isQ ? q_b : v_b;
    const int nb = isQ ? n0 : (n0 - DHN);

    for (int idx = tid; idx < 160 * 64; idx += 256) {
      int k = idx >> 6, n = idx & 63;
      float v = (k < DD + DT) ? wsrc[(size_t)k * DHN + nb + n] : 0.f;
      BC_s[n * LDA + k] = f2bf(v);
    }
    __syncthreads();

    f32x4 acc[2][4];
#pragma unroll
    for (int mi = 0; mi < 2; ++mi)
#pragma unroll
      for (int ni = 0; ni < 4; ++ni) { f32x4 zz = {0.f,0.f,0.f,0.f}; acc[mi][ni] = zz; }
    const int mb = w * 32;
#pragma unroll
    for (int kc = 0; kc < 5; ++kc) {
      const int ko = kc * 32 + ((lane >> 4) << 3);
      short8v af[2], bf[4];
#pragma unroll
      for (int mi = 0; mi < 2; ++mi)
        af[mi] = *(const short8v*)&A_s[(mb + mi*16 + (lane & 15)) * LDA + ko];
#pragma unroll
      for (int ni = 0; ni < 4; ++ni)
        bf[ni] = *(const short8v*)&BC_s[(ni*16 + (lane & 15)) * LDA + ko];
#pragma unroll
      for (int mi = 0; mi < 2; ++mi)
#pragma unroll
        for (int ni = 0; ni < 4; ++ni)
          acc[mi][ni] = __builtin_amdgcn_mfma_f32_16x16x32_bf16(af[mi], bf[ni], acc[mi][ni], 0, 0, 0);
    }
    __syncthreads();

#pragma unroll
    for (int mi = 0; mi < 2; ++mi)
#pragma unroll
      for (int ni = 0; ni < 4; ++ni) {
        int cl = ni*16 + (lane & 15);
        float bb = bias[nb + cl];
#pragma unroll
        for (int q = 0; q < 4; ++q) {
          int t = mb + mi*16 + ((lane >> 4) << 2) + q;
          float vv = acc[mi][ni][q] + bb;
          if (isQ) vv = fmaxf(vv, 0.f);
          BC_s[t * 66 + cl] = f2bf(vv);
        }
      }
    __syncthreads();

    if (isQ) {
      for (int idx = tid; idx < 4 * 512; idx += 256) {
        int d4l = idx >> 9, r = idx & 511;
        int t = r >> 2, h = r & 3;
        const unsigned short* cr = &BC_s[t * 66 + d4l * 16 + h];
        uint2v u;
        u.x = (unsigned)cr[0] | ((unsigned)cr[4]  << 16);
        u.y = (unsigned)cr[8] | ((unsigned)cr[12] << 16);
        Qp4[((size_t)b * 64 + (n0 >> 4) + d4l) * 512 + r] = u;
      }
    } else {
      int c0 = (n0 - DHN) >> 1;
      for (int idx = tid; idx < 128 * 32; idx += 256) {
        int t = idx >> 5, c2 = idx & 31;
        const unsigned short* cr = &BC_s[t * 66 + c2 * 2];
        Vws[((size_t)b * 128 + t) * 512 + c0 + c2] = (unsigned)cr[0] | ((unsigned)cr[1] << 16);
      }
    }
    __syncthreads();
  }
}

// ---------------------------------------------------------------------------
// Kernel 3: 127-step recurrence, one block (512 thr) per batch element.
// Q/V persistent state as 192 NAMED SCALARS (REP64 macros) — never an array,
// never address-taken, so SROA cannot park it in scratch (R2-R5 failure:
// 64-elem arrays -> alloca -> 12 GB scratch traffic, WRITE_SIZE 10x logical).
// waves_per_eu(2,2): 8 waves/CU (our grid = 1 block/CU) -> 256-VGPR budget.
// ---------------------------------------------------------------------------
__global__
__attribute__((amdgpu_flat_work_group_size(512, 512), amdgpu_waves_per_eu(2, 2)))
void recur_kernel(
    const float* __restrict__ x, const float* __restrict__ bvec,
    const float* __restrict__ m, const float* __restrict__ eps,
    const float* __restrict__ bk_w, const float* __restrict__ bk_b,
    const float* __restrict__ bv_w, const float* __restrict__ bv_b,
    const float* __restrict__ hk_b, const float* __restrict__ hv_b,
    const float* __restrict__ mu1_w, const float* __restrict__ mu1_b,
    const float* __restrict__ sg1_w, const float* __restrict__ sg1_b,
    const float* __restrict__ mut_b, const float* __restrict__ sgt_b,
    const unsigned* __restrict__ hkp, const unsigned* __restrict__ hvp,
    const unsigned* __restrict__ mutp, const unsigned* __restrict__ sgtp,
    const uint2v* __restrict__ Qp4, const unsigned* __restrict__ Vws,
    float* __restrict__ out)
{
  const int b    = blockIdx.x;
  const int tid  = threadIdx.x;
  const int lane = tid & 63;
  const int wv   = tid >> 6;

  __shared__ __align__(16) float key_s[DH];
  __shared__ __align__(16) float sc[512];
  __shared__ __align__(16) float ppair[2][128][2];   // [hpair][t][h&1]
  __shared__ __align__(16) float val_s[DHN];
  __shared__ __align__(16) float ht_s[DHN];
  __shared__ __align__(16) float red[2 * 8 * 64];
  __shared__ __align__(16) float z_s[DS];
  __shared__ __align__(16) float xb[DD + DB];
  __shared__ float mask_s[128];
  __shared__ __align__(16) float hkb_s[DH];
  __shared__ __align__(16) float hvb_s[DHN];
  __shared__ float mtb_s[DS], stb_s[DS];

  // ---- preload small constants ----
  if (tid < DD + DB) xb[tid] = (tid < DD) ? x[(size_t)b * T_ * DD + tid] : bvec[b * DB + (tid - DD)];
  if (tid >= 256 && tid < 512) hkb_s[tid - 256] = hk_b[tid - 256];
  for (int i = tid; i < DHN; i += 512) hvb_s[i] = hv_b[i];
  if (tid < DS) { mtb_s[tid] = mut_b[tid]; stb_s[tid] = sgt_b[tid]; }
  if (tid < 128) {
    ppair[0][tid][0] = 0.f; ppair[0][tid][1] = 0.f;
    ppair[1][tid][0] = 0.f; ppair[1][tid][1] = 0.f;
  }

  // ---- mask[t] ----
  for (int t = wv; t < TP; t += 8) {
    const float* mr = m + ((size_t)b * T_ + 1 + t) * DD;
    float s = mr[lane] + mr[lane + 64];
    for (int o = 1; o < 64; o <<= 1) s += __shfl_xor(s, o);
    if (lane == 0) mask_s[t] = (s > 0.f) ? 1.f : 0.f;
  }
  if (tid == 0) mask_s[127] = 0.f;

  // ---- persistent Q (bf16, 128 scalars) and V (fp8-packed, 64 scalars) ----
#define DECLQV(n) unsigned qx##n, qy##n, vv##n;
  REP64(DECLQV)
#undef DECLQV

  {
    const uint2v* qp = Qp4 + (size_t)b * 64 * 512 + tid;
#define LDQ(n) { uint2v tq = qp[n * 512]; qx##n = tq.x; qy##n = tq.y; }
    REP64(LDQ)
#undef LDQ
  }
  {
    const unsigned* vp = Vws + (size_t)b * 128 * 512 + tid;
#define LDV(n) { unsigned w0 = vp[(2*n) * 512]; unsigned w1 = vp[(2*n+1) * 512]; \
    int pk8 = __builtin_amdgcn_cvt_pk_fp8_f32(bf16lo(w0), bf16hi(w0), 0, false); \
    pk8     = __builtin_amdgcn_cvt_pk_fp8_f32(bf16lo(w1), bf16hi(w1), pk8, true); \
    vv##n = (unsigned)pk8; }
    REP64(LDV)
#undef LDV
  }
  __syncthreads();

  const int hp = tid & 1;

  // ================= unified steps 0..126 =================
  for (int st = 0; st < TP; ++st) {
    // ---------- key/val ----------
    if (st == 0) {
      if (tid < 256) {
        float acc = bk_b[tid];
        for (int s = 0; s < DD + DB; ++s) acc = fmaf(xb[s], bk_w[s * DH + tid], acc);
        key_s[tid] = fmaxf(acc, 0.f);
      } else {
        int c = tid - 256;
        float a0 = bv_b[c], a1 = bv_b[c + 256], a2 = bv_b[c + 512], a3 = bv_b[c + 768];
        for (int s = 0; s < DD + DB; ++s) {
          float xs = xb[s];
          const float* r = bv_w + (size_t)s * DHN + c;
          a0 = fmaf(xs, r[0], a0);   a1 = fmaf(xs, r[256], a1);
          a2 = fmaf(xs, r[512], a2); a3 = fmaf(xs, r[768], a3);
        }
        val_s[c] = a0; val_s[c + 256] = a1; val_s[c + 512] = a2; val_s[c + 768] = a3;
      }
    } else {
      if (tid < 256) {
        float av = hvb_s[tid];
        float ak = hkb_s[tid];
#pragma unroll 8
        for (int s2 = 0; s2 < 32; ++s2) {
          float2 zz = *(const float2*)&z_s[s2 * 2];
          unsigned w0 = hvp[s2 * 1024 + tid];
          unsigned wq = hkp[s2 * 256 + tid];
          av = fmaf(zz.x, bf16lo(w0), av); av = fmaf(zz.y, bf16hi(w0), av);
          ak = fmaf(zz.x, bf16lo(wq), ak); ak = fmaf(zz.y, bf16hi(wq), ak);
        }
        val_s[tid] = av;
        key_s[tid] = fmaxf(ak, 0.f);
      } else {
        const int c = tid;
        float a0 = hvb_s[c], a1 = hvb_s[c + 256], a2 = hvb_s[c + 512];
#pragma unroll 4
        for (int s2 = 0; s2 < 32; ++s2) {
          float2 zz = *(const float2*)&z_s[s2 * 2];
          unsigned w0 = hvp[s2 * 1024 + c];
          unsigned w1 = hvp[s2 * 1024 + c + 256];
          unsigned w2 = hvp[s2 * 1024 + c + 512];
          a0 = fmaf(zz.x, bf16lo(w0), a0); a0 = fmaf(zz.y, bf16hi(w0), a0);
          a1 = fmaf(zz.x, bf16lo(w1), a1); a1 = fmaf(zz.y, bf16hi(w1), a1);
          a2 = fmaf(zz.x, bf16lo(w2), a2); a2 = fmaf(zz.y, bf16hi(w2), a2);
        }
        val_s[c] = a0; val_s[c + 256] = a1; val_s[c + 512] = a2;
      }
    }
    __syncthreads();

    // ---------- scores: thread r=tid handles (t=r>>2, h=r&3) ----------
    {
      float acc0 = 0.f, acc1 = 0.f;
#define SC4(n) { float4 kk = *(const float4*)&key_s[n * 4]; \
      acc0 = fmaf(bf16lo(qx##n), kk.x, acc0); \
      acc1 = fmaf(bf16hi(qx##n), kk.y, acc1); \
      acc0 = fmaf(bf16lo(qy##n), kk.z, acc0); \
      acc1 = fmaf(bf16hi(qy##n), kk.w, acc1); }
      REP64(SC4)
#undef SC4
      sc[tid] = (mask_s[tid >> 2] > 0.f) ? (acc0 + acc1) * 0.0625f : -1e9f;
    }
    __syncthreads();

    // ---------- softmax over t, per head h = wave 0..3 ----------
    if (tid < 256) {
      int h = wv, l = lane;
      float v1 = sc[l * 4 + h];
      float v2 = (l + 64 < TP) ? sc[(l + 64) * 4 + h] : -3.0e38f;
      float mm = fmaxf(v1, v2);
      for (int o = 1; o < 64; o <<= 1) mm = fmaxf(mm, __shfl_xor(mm, o));
      float e1 = __expf(v1 - mm);
      float e2 = (l + 64 < TP) ? __expf(v2 - mm) : 0.f;
      float ssum = e1 + e2;
      for (int o = 1; o < 64; o <<= 1) ssum += __shfl_xor(ssum, o);
      float inv = 1.f / ssum;
      ppair[h >> 1][l][h & 1] = e1 * inv;
      if (l + 64 < TP) ppair[h >> 1][l + 64][h & 1] = e2 * inv;
    }
    __syncthreads();

    // ---------- PV from fp8 scalars: thread owns cols 2tid, 2tid+1 ----------
    {
      float a0 = 0.f, a1 = 0.f;
#define PV4(n) { float4 pp = *(const float4*)&ppair[hp][2 * n][0]; \
      f32x2 v01 = __builtin_amdgcn_cvt_pk_f32_fp8(vv##n, false); \
      f32x2 v23 = __builtin_amdgcn_cvt_pk_f32_fp8(vv##n, true); \
      a0 = fmaf(pp.x, v01.x, a0); a1 = fmaf(pp.y, v01.y, a1); \
      a0 = fmaf(pp.z, v23.x, a0); a1 = fmaf(pp.w, v23.y, a1); }
      REP64(PV4)
#undef PV4
      int j = tid * 2;
      float2 vvp = *(const float2*)&val_s[j];
      float2 hh2;
      hh2.x = fmaxf(0.5f * (a0 + vvp.x), 0.f);
      hh2.y = fmaxf(0.5f * (a1 + vvp.y), 0.f);
      *(float2*)&ht_s[j] = hh2;
    }
    __syncthreads();

    // ---------- mu/sg matvec ----------
    {
      int k = tid & 63, g = tid >> 6;
      float am, as_;
      if (st == 0) {
        am = 0.f; as_ = 0.f;
        for (int jl = 0; jl < 128; ++jl) {
          int j = g * 128 + jl;
          float hj = ht_s[j];
          am  = fmaf(hj, mu1_w[(size_t)j * 64 + k], am);
          as_ = fmaf(hj, sg1_w[(size_t)j * 64 + k], as_);
        }
      } else {
        float am0 = 0.f, am1 = 0.f, as0 = 0.f, as1 = 0.f;
#pragma unroll 4
        for (int j2 = 0; j2 < 64; ++j2) {
          int J2 = g * 64 + j2;
          float2 hh = *(const float2*)&ht_s[J2 * 2];
          unsigned wm = mutp[J2 * 64 + k];
          unsigned ws = sgtp[J2 * 64 + k];
          am0 = fmaf(hh.x, bf16lo(wm), am0);
          am1 = fmaf(hh.y, bf16hi(wm), am1);
          as0 = fmaf(hh.x, bf16lo(ws), as0);
          as1 = fmaf(hh.y, bf16hi(ws), as1);
        }
        am = am0 + am1; as_ = as0 + as1;
      }
      red[g * 64 + k] = am; red[512 + g * 64 + k] = as_;
    }
    __syncthreads();

    if (tid < 64) {
      float mu = (st == 0) ? mu1_b[tid] : mtb_s[tid];
      float sl = (st == 0) ? sg1_b[tid] : stb_s[tid];
      for (int g = 0; g < 8; ++g) { mu += red[g * 64 + tid]; sl += red[512 + g * 64 + tid]; }
      float sg = softplus_f(sl);
      float z  = fmaf(sg, eps[((size_t)st * BS + b) * 64 + tid], mu);
      size_t o0 = ((size_t)b * TP + st) * 64 + tid;
      out[o0] = z; out[OFFV + o0] = mu; out[2ull * OFFV + o0] = sg;
      z_s[tid] = z;
    }
    __syncthreads();
  }
}

// ---------------------------------------------------------------------------
extern "C" void kernel_launch(void* const* d_in, const int* in_sizes, int n_in,
                              void* d_out, int out_size, void* d_ws, size_t ws_size,
                              hipStream_t stream) {
  const float* x    = (const float*)d_in[0];
  const float* a    = (const float*)d_in[1];
  const float* m    = (const float*)d_in[2];
  const float* bvec = (const float*)d_in[3];
  const float* eps  = (const float*)d_in[4];
  const float* bk_w = (const float*)d_in[5];
  const float* bk_b = (const float*)d_in[6];
  const float* bv_w = (const float*)d_in[7];
  const float* bv_b = (const float*)d_in[8];
  const float* q_w  = (const float*)d_in[9];
  const float* q_b  = (const float*)d_in[10];
  const float* v_w  = (const float*)d_in[11];
  const float* v_b  = (const float*)d_in[12];
  const float* hk_w = (const float*)d_in[13];
  const float* hk_b = (const float*)d_in[14];
  const float* hv_w = (const float*)d_in[15];
  const float* hv_b = (const float*)d_in[16];
  const float* mu1_w= (const float*)d_in[17];
  const float* mu1_b= (const float*)d_in[18];
  const float* sg1_w= (const float*)d_in[19];
  const float* sg1_b= (const float*)d_in[20];
  const float* mut_w= (const float*)d_in[21];
  const float* mut_b= (const float*)d_in[22];
  const float* sgt_w= (const float*)d_in[23];
  const float* sgt_b= (const float*)d_in[24];

  char* ws = (char*)d_ws;
  uint2v*   Qp4  = (uint2v*)ws;
  unsigned* Vws  = (unsigned*)(ws + (64ull << 20));
  unsigned* hkp  = (unsigned*)(ws + (128ull << 20));
  unsigned* hvp  = hkp + 32 * 256;
  unsigned* mutp = hvp + 32 * 1024;
  unsigned* sgtp = mutp + 512 * 64;

  pack_w_kernel<<<dim3(128), dim3(256), 0, stream>>>(hk_w, hv_w, mut_w, sgt_w,
                                                     hkp, hvp, mutp, sgtp);
  proj_kernel<<<dim3(256), dim3(256), 0, stream>>>(x, a, q_w, q_b, v_w, v_b, Qp4, Vws);
  recur_kernel<<<dim3(256), dim3(512), 0, stream>>>(x, bvec, m, eps,
      bk_w, bk_b, bv_w, bv_b, hk_b, hv_b,
      mu1_w, mu1_b, sg1_w, sg1_b, mut_b, sgt_b,
      hkp, hvp, mutp, sgtp, Qp4, Vws, (float*)d_out);
}

// Round 7
// 8143.641 us; speedup vs baseline: 1.0632x; 1.0632x over previous
//
#include <hip/hip_runtime.h>
#include <hip/hip_bf16.h>
#include <stdint.h>

// Sizes from the reference
#define BS   256
#define T_   128
#define TP   127      // T-1
#define DD   128
#define DT   16
#define DB   32
#define DH   256
#define NH   4
#define DS   64
#define DHN  1024

#define OFFV (256u*127u*64u)   // 2080768, size of each output tensor

typedef __attribute__((ext_vector_type(8))) short short8v;
typedef __attribute__((ext_vector_type(4))) float f32x4;
typedef __attribute__((ext_vector_type(2))) float f32x2;
typedef __attribute__((ext_vector_type(2))) unsigned int uint2v;

__device__ __forceinline__ float bf16lo(unsigned u){ return __uint_as_float(u << 16); }
__device__ __forceinline__ float bf16hi(unsigned u){ return __uint_as_float(u & 0xffff0000u); }
__device__ __forceinline__ unsigned short f2bf(float f){
  unsigned u = __float_as_uint(f);
  u += 0x7fffu + ((u >> 16) & 1u);   // RNE
  return (unsigned short)(u >> 16);
}
__device__ __forceinline__ unsigned pk2(float lo, float hi){
  return (unsigned)f2bf(lo) | ((unsigned)f2bf(hi) << 16);
}
__device__ __forceinline__ float softplus_f(float x){
  return fmaxf(x, 0.f) + log1pf(__expf(-fabsf(x)));
}

#define REP32(M) M(0) M(1) M(2) M(3) M(4) M(5) M(6) M(7) M(8) M(9) M(10) M(11) \
  M(12) M(13) M(14) M(15) M(16) M(17) M(18) M(19) M(20) M(21) M(22) M(23) \
  M(24) M(25) M(26) M(27) M(28) M(29) M(30) M(31)

// ---------------------------------------------------------------------------
// Kernel 1: pack recurrent weights to bf16, paired along the reduction dim.
// ---------------------------------------------------------------------------
__global__ __launch_bounds__(256) void pack_w_kernel(
    const float* __restrict__ hk_w, const float* __restrict__ hv_w,
    const float* __restrict__ mut_w, const float* __restrict__ sgt_w,
    unsigned* __restrict__ hkp, unsigned* __restrict__ hvp,
    unsigned* __restrict__ mutp, unsigned* __restrict__ sgtp)
{
  int i = blockIdx.x * 256 + threadIdx.x;
  if (i < 32*256) { int s2 = i >> 8, d = i & 255;
    hkp[i] = pk2(hk_w[(2*s2)*256 + d], hk_w[(2*s2+1)*256 + d]); }
  if (i < 32*1024) { int s2 = i >> 10, j = i & 1023;
    hvp[i] = pk2(hv_w[(2*s2)*1024 + j], hv_w[(2*s2+1)*1024 + j]); }
  if (i < 512*64) { int J2 = i >> 6, k = i & 63;
    mutp[i] = pk2(mut_w[(2*J2)*64 + k], mut_w[(2*J2+1)*64 + k]);
    sgtp[i] = pk2(sgt_w[(2*J2)*64 + k], sgt_w[(2*J2+1)*64 + k]); }
}

// ---------------------------------------------------------------------------
// Kernel 2: projection GEMM (MFMA bf16 16x16x32).  One block per b.
// ---------------------------------------------------------------------------
#define LDA 168

__global__ __launch_bounds__(256) void proj_kernel(
    const float* __restrict__ x, const float* __restrict__ a,
    const float* __restrict__ q_w, const float* __restrict__ q_b,
    const float* __restrict__ v_w, const float* __restrict__ v_b,
    uint2v* __restrict__ Qp4, unsigned* __restrict__ Vws)
{
  const int b    = blockIdx.x;
  const int tid  = threadIdx.x;
  const int lane = tid & 63;
  const int w    = tid >> 6;

  __shared__ __align__(16) unsigned short A_s[128 * LDA];
  __shared__ __align__(16) unsigned short BC_s[64 * LDA];

  for (int idx = tid; idx < 128 * DD; idx += 256) {
    int t = idx >> 7, k = idx & 127;
    float v = (t < TP) ? x[((size_t)b * T_ + 1 + t) * DD + k] : 0.f;
    A_s[t * LDA + k] = f2bf(v);
  }
  for (int idx = tid; idx < 128 * 40; idx += 256) {
    int t = idx / 40, kk = idx % 40;
    float v = (t < TP && kk < DT) ? a[((size_t)b * T_ + t) * DT + kk] : 0.f;
    A_s[t * LDA + 128 + kk] = f2bf(v);
  }
  __syncthreads();

  for (int nt = 0; nt < 32; ++nt) {
    const int n0 = nt * 64;
    const bool isQ = (n0 < DHN);
    const float* wsrc = isQ ? q_w : v_w;
    const float* bias = isQ ? q_b : v_b;
    const int nb = isQ ? n0 : (n0 - DHN);

    for (int idx = tid; idx < 160 * 64; idx += 256) {
      int k = idx >> 6, n = idx & 63;
      float v = (k < DD + DT) ? wsrc[(size_t)k * DHN + nb + n] : 0.f;
      BC_s[n * LDA + k] = f2bf(v);
    }
    __syncthreads();

    f32x4 acc[2][4];
#pragma unroll
    for (int mi = 0; mi < 2; ++mi)
#pragma unroll
      for (int ni = 0; ni < 4; ++ni) { f32x4 zz = {0.f,0.f,0.f,0.f}; acc[mi][ni] = zz; }
    const int mb = w * 32;
#pragma unroll
    for (int kc = 0; kc < 5; ++kc) {
      const int ko = kc * 32 + ((lane >> 4) << 3);
      short8v af[2], bf[4];
#pragma unroll
      for (int mi = 0; mi < 2; ++mi)
        af[mi] = *(const short8v*)&A_s[(mb + mi*16 + (lane & 15)) * LDA + ko];
#pragma unroll
      for (int ni = 0; ni < 4; ++ni)
        bf[ni] = *(const short8v*)&BC_s[(ni*16 + (lane & 15)) * LDA + ko];
#pragma unroll
      for (int mi = 0; mi < 2; ++mi)
#pragma unroll
        for (int ni = 0; ni < 4; ++ni)
          acc[mi][ni] = __builtin_amdgcn_mfma_f32_16x16x32_bf16(af[mi], bf[ni], acc[mi][ni], 0, 0, 0);
    }
    __syncthreads();

#pragma unroll
    for (int mi = 0; mi < 2; ++mi)
#pragma unroll
      for (int ni = 0; ni < 4; ++ni) {
        int cl = ni*16 + (lane & 15);
        float bb = bias[nb + cl];
#pragma unroll
        for (int q = 0; q < 4; ++q) {
          int t = mb + mi*16 + ((lane >> 4) << 2) + q;
          float vv = acc[mi][ni][q] + bb;
          if (isQ) vv = fmaxf(vv, 0.f);
          BC_s[t * 66 + cl] = f2bf(vv);
        }
      }
    __syncthreads();

    if (isQ) {
      for (int idx = tid; idx < 4 * 512; idx += 256) {
        int d4l = idx >> 9, r = idx & 511;
        int t = r >> 2, h = r & 3;
        const unsigned short* cr = &BC_s[t * 66 + d4l * 16 + h];
        uint2v u;
        u.x = (unsigned)cr[0] | ((unsigned)cr[4]  << 16);
        u.y = (unsigned)cr[8] | ((unsigned)cr[12] << 16);
        Qp4[((size_t)b * 64 + (n0 >> 4) + d4l) * 512 + r] = u;
      }
    } else {
      int c0 = (n0 - DHN) >> 1;
      for (int idx = tid; idx < 128 * 32; idx += 256) {
        int t = idx >> 5, c2 = idx & 31;
        const unsigned short* cr = &BC_s[t * 66 + c2 * 2];
        Vws[((size_t)b * 128 + t) * 512 + c0 + c2] = (unsigned)cr[0] | ((unsigned)cr[1] << 16);
      }
    }
    __syncthreads();
  }
}

// ---------------------------------------------------------------------------
// Kernel 3: 127-step recurrence.  One block per b, 1024 threads (16 waves).
// Per-thread persistent state HALVED vs R2-R6 so it fits the natural
// 128-VGPR cap (2048-reg pool / 16 waves): Q fp8 half-row (32 dwords) +
// V fp8 one column (32 dwords) = 64 persistent regs.  Scores are computed
// as two half-dots (thread tid: row r=tid&511, d-half tid>>9) summed in LDS.
// ---------------------------------------------------------------------------
__global__ __launch_bounds__(1024)
void recur_kernel(
    const float* __restrict__ x, const float* __restrict__ bvec,
    const float* __restrict__ m, const float* __restrict__ eps,
    const float* __restrict__ bk_w, const float* __restrict__ bk_b,
    const float* __restrict__ bv_w, const float* __restrict__ bv_b,
    const float* __restrict__ hk_b, const float* __restrict__ hv_b,
    const float* __restrict__ mu1_w, const float* __restrict__ mu1_b,
    const float* __restrict__ sg1_w, const float* __restrict__ sg1_b,
    const float* __restrict__ mut_b, const float* __restrict__ sgt_b,
    const unsigned* __restrict__ hkp, const unsigned* __restrict__ hvp,
    const unsigned* __restrict__ mutp, const unsigned* __restrict__ sgtp,
    const uint2v* __restrict__ Qp4, const unsigned* __restrict__ Vws,
    float* __restrict__ out)
{
  const int b    = blockIdx.x;
  const int tid  = threadIdx.x;
  const int lane = tid & 63;
  const int wvid = tid >> 6;          // 0..15

  __shared__ __align__(16) float key_s[DH];
  __shared__ __align__(16) float sc[1024];       // partial scores [dhalf][r]
  __shared__ __align__(16) float p_T[4][128];    // p transposed [h][t]
  __shared__ __align__(16) float val_s[DHN];
  __shared__ __align__(16) float ht_s[DHN];
  __shared__ __align__(16) float red[16 * 64];   // [sel*8+g][k]
  __shared__ __align__(16) float z_s[DS];
  __shared__ __align__(16) float xb[DD + DB];
  __shared__ float mask_s[128];
  __shared__ __align__(16) float hkb_s[DH];
  __shared__ __align__(16) float hvb_s[DHN];
  __shared__ float mtb_s[DS], stb_s[DS];

  // ---- preload small constants ----
  if (tid < DD + DB) xb[tid] = (tid < DD) ? x[(size_t)b * T_ * DD + tid] : bvec[b * DB + (tid - DD)];
  if (tid >= 256 && tid < 512) hkb_s[tid - 256] = hk_b[tid - 256];
  hvb_s[tid] = hv_b[tid];
  if (tid < DS) { mtb_s[tid] = mut_b[tid]; stb_s[tid] = sgt_b[tid]; }
  if (tid < 512) ((float*)p_T)[tid] = 0.f;   // ensures p_T[h][127] stays 0

  // ---- mask[t] ----
  for (int t = wvid; t < TP; t += 16) {
    const float* mr = m + ((size_t)b * T_ + 1 + t) * DD;
    float s = mr[lane] + mr[lane + 64];
    for (int o = 1; o < 64; o <<= 1) s += __shfl_xor(s, o);
    if (lane == 0) mask_s[t] = (s > 0.f) ? 1.f : 0.f;
  }

  const int r     = tid & 511;        // score row (t*4+h)
  const int dhalf = tid >> 9;         // 0 or 1: which 128-d half
  const int hW    = tid >> 8;         // head for PV (uniform per wave)

  // ---- persistent Q fp8 (32 dwords) + V fp8 (32 dwords), named scalars ----
#define DECLQV(n) unsigned qq##n, vq##n;
  REP32(DECLQV)
#undef DECLQV

  {
    const uint2v* qp = Qp4 + ((size_t)b * 64 + dhalf * 32) * 512 + r;
#define LDQ(n) { uint2v tq = qp[n * 512]; \
    int pk8 = __builtin_amdgcn_cvt_pk_fp8_f32(bf16lo(tq.x), bf16hi(tq.x), 0, false); \
    pk8     = __builtin_amdgcn_cvt_pk_fp8_f32(bf16lo(tq.y), bf16hi(tq.y), pk8, true); \
    qq##n = (unsigned)pk8; }
    REP32(LDQ)
#undef LDQ
  }
  {
    const unsigned* vp = Vws + (size_t)b * 128 * 512 + (tid >> 1);
    const bool vhi = (tid & 1);
#define LDV(n) { unsigned w0 = vp[(4*n)*512], w1 = vp[(4*n+1)*512]; \
    unsigned w2 = vp[(4*n+2)*512], w3 = vp[(4*n+3)*512]; \
    float f0 = vhi ? bf16hi(w0) : bf16lo(w0); float f1 = vhi ? bf16hi(w1) : bf16lo(w1); \
    float f2 = vhi ? bf16hi(w2) : bf16lo(w2); float f3 = vhi ? bf16hi(w3) : bf16lo(w3); \
    int pk8 = __builtin_amdgcn_cvt_pk_fp8_f32(f0, f1, 0, false); \
    pk8     = __builtin_amdgcn_cvt_pk_fp8_f32(f2, f3, pk8, true); \
    vq##n = (unsigned)pk8; }
    REP32(LDV)
#undef LDV
  }
  __syncthreads();

  // ================= unified steps 0..126 =================
  for (int st = 0; st < TP; ++st) {
    // ---------- key (256 cols, threads<256) / val (1024 cols, all) ----------
    if (st == 0) {
      float av = bv_b[tid];
      for (int s = 0; s < DD + DB; ++s) av = fmaf(xb[s], bv_w[(size_t)s * DHN + tid], av);
      val_s[tid] = av;
      if (tid < 256) {
        float ak = bk_b[tid];
        for (int s = 0; s < DD + DB; ++s) ak = fmaf(xb[s], bk_w[s * DH + tid], ak);
        key_s[tid] = fmaxf(ak, 0.f);
      }
    } else {
      float av = hvb_s[tid];
#pragma unroll 8
      for (int s2 = 0; s2 < 32; ++s2) {
        float2 zz = *(const float2*)&z_s[s2 * 2];
        unsigned w0 = hvp[s2 * 1024 + tid];
        av = fmaf(zz.x, bf16lo(w0), av); av = fmaf(zz.y, bf16hi(w0), av);
      }
      val_s[tid] = av;
      if (tid < 256) {
        float ak = hkb_s[tid];
#pragma unroll 8
        for (int s2 = 0; s2 < 32; ++s2) {
          float2 zz = *(const float2*)&z_s[s2 * 2];
          unsigned wq = hkp[s2 * 256 + tid];
          ak = fmaf(zz.x, bf16lo(wq), ak); ak = fmaf(zz.y, bf16hi(wq), ak);
        }
        key_s[tid] = fmaxf(ak, 0.f);
      }
    }
    __syncthreads();

    // ---------- half-scores: thread handles row r, d in [dhalf*128, +128) ----
    {
      const float* kb = &key_s[dhalf * 128];
      float acc = 0.f;
#define SC4(n) { float4 kk = *(const float4*)&kb[4 * n]; \
      f32x2 a01 = __builtin_amdgcn_cvt_pk_f32_fp8(qq##n, false); \
      f32x2 a23 = __builtin_amdgcn_cvt_pk_f32_fp8(qq##n, true); \
      acc = fmaf(a01.x, kk.x, acc); acc = fmaf(a01.y, kk.y, acc); \
      acc = fmaf(a23.x, kk.z, acc); acc = fmaf(a23.y, kk.w, acc); }
      REP32(SC4)
#undef SC4
      sc[tid] = acc;    // raw partial (scale+mask applied in softmax)
    }
    __syncthreads();

    // ---------- softmax over t, per head h = wave 0..3 (tid<256) ----------
    if (tid < 256) {
      int h = wvid, l = lane;
      int i1 = l * 4 + h;
      float v1 = (mask_s[l] > 0.f) ? (sc[i1] + sc[512 + i1]) * 0.0625f : -1e9f;
      float v2 = -3.0e38f;
      if (l + 64 < TP) {
        int i2 = (l + 64) * 4 + h;
        v2 = (mask_s[l + 64] > 0.f) ? (sc[i2] + sc[512 + i2]) * 0.0625f : -1e9f;
      }
      float mm = fmaxf(v1, v2);
      for (int o = 1; o < 64; o <<= 1) mm = fmaxf(mm, __shfl_xor(mm, o));
      float e1 = __expf(v1 - mm);
      float e2 = (l + 64 < TP) ? __expf(v2 - mm) : 0.f;
      float ssum = e1 + e2;
      for (int o = 1; o < 64; o <<= 1) ssum += __shfl_xor(ssum, o);
      float inv = 1.f / ssum;
      p_T[h][l] = e1 * inv;
      if (l + 64 < TP) p_T[h][l + 64] = e2 * inv;
    }
    __syncthreads();

    // ---------- PV: thread owns col j=tid; p_T reads are wave-uniform ----------
    {
      float a = 0.f;
#define PV4(n) { float4 pp = *(const float4*)&p_T[hW][4 * n]; \
      f32x2 v01 = __builtin_amdgcn_cvt_pk_f32_fp8(vq##n, false); \
      f32x2 v23 = __builtin_amdgcn_cvt_pk_f32_fp8(vq##n, true); \
      a = fmaf(pp.x, v01.x, a); a = fmaf(pp.y, v01.y, a); \
      a = fmaf(pp.z, v23.x, a); a = fmaf(pp.w, v23.y, a); }
      REP32(PV4)
#undef PV4
      ht_s[tid] = fmaxf(0.5f * (a + val_s[tid]), 0.f);
    }
    __syncthreads();

    // ---------- mu/sg matvec: k=tid&63, sel=(tid>>6)&1, group g=tid>>7 ----------
    {
      int k = tid & 63, sel = (tid >> 6) & 1, g = tid >> 7;
      float acc;
      if (st == 0) {
        const float* wsel = sel ? sg1_w : mu1_w;
        acc = 0.f;
        for (int jl = g * 128; jl < g * 128 + 128; ++jl)
          acc = fmaf(ht_s[jl], wsel[(size_t)jl * 64 + k], acc);
      } else {
        const unsigned* wp = sel ? sgtp : mutp;
        float a0 = 0.f, a1 = 0.f;
#pragma unroll 4
        for (int j2 = g * 64; j2 < g * 64 + 64; ++j2) {
          float2 hh = *(const float2*)&ht_s[j2 * 2];
          unsigned wm = wp[j2 * 64 + k];
          a0 = fmaf(hh.x, bf16lo(wm), a0);
          a1 = fmaf(hh.y, bf16hi(wm), a1);
        }
        acc = a0 + a1;
      }
      red[(sel * 8 + g) * 64 + k] = acc;
    }
    __syncthreads();

    if (tid < 64) {
      float mu = (st == 0) ? mu1_b[tid] : mtb_s[tid];
      float sl = (st == 0) ? sg1_b[tid] : stb_s[tid];
#pragma unroll
      for (int g = 0; g < 8; ++g) { mu += red[g * 64 + tid]; sl += red[(8 + g) * 64 + tid]; }
      float sg = softplus_f(sl);
      float z  = fmaf(sg, eps[((size_t)st * BS + b) * 64 + tid], mu);
      size_t o0 = ((size_t)b * TP + st) * 64 + tid;
      out[o0] = z; out[OFFV + o0] = mu; out[2ull * OFFV + o0] = sg;
      z_s[tid] = z;
    }
    __syncthreads();
  }
}

// ---------------------------------------------------------------------------
extern "C" void kernel_launch(void* const* d_in, const int* in_sizes, int n_in,
                              void* d_out, int out_size, void* d_ws, size_t ws_size,
                              hipStream_t stream) {
  const float* x    = (const float*)d_in[0];
  const float* a    = (const float*)d_in[1];
  const float* m    = (const float*)d_in[2];
  const float* bvec = (const float*)d_in[3];
  const float* eps  = (const float*)d_in[4];
  const float* bk_w = (const float*)d_in[5];
  const float* bk_b = (const float*)d_in[6];
  const float* bv_w = (const float*)d_in[7];
  const float* bv_b = (const float*)d_in[8];
  const float* q_w  = (const float*)d_in[9];
  const float* q_b  = (const float*)d_in[10];
  const float* v_w  = (const float*)d_in[11];
  const float* v_b  = (const float*)d_in[12];
  const float* hk_w = (const float*)d_in[13];
  const float* hk_b = (const float*)d_in[14];
  const float* hv_w = (const float*)d_in[15];
  const float* hv_b = (const float*)d_in[16];
  const float* mu1_w= (const float*)d_in[17];
  const float* mu1_b= (const float*)d_in[18];
  const float* sg1_w= (const float*)d_in[19];
  const float* sg1_b= (const float*)d_in[20];
  const float* mut_w= (const float*)d_in[21];
  const float* mut_b= (const float*)d_in[22];
  const float* sgt_w= (const float*)d_in[23];
  const float* sgt_b= (const float*)d_in[24];

  char* ws = (char*)d_ws;
  uint2v*   Qp4  = (uint2v*)ws;
  unsigned* Vws  = (unsigned*)(ws + (64ull << 20));
  unsigned* hkp  = (unsigned*)(ws + (128ull << 20));
  unsigned* hvp  = hkp + 32 * 256;
  unsigned* mutp = hvp + 32 * 1024;
  unsigned* sgtp = mutp + 512 * 64;

  pack_w_kernel<<<dim3(128), dim3(256), 0, stream>>>(hk_w, hv_w, mut_w, sgt_w,
                                                     hkp, hvp, mutp, sgtp);
  proj_kernel<<<dim3(256), dim3(256), 0, stream>>>(x, a, q_w, q_b, v_w, v_b, Qp4, Vws);
  recur_kernel<<<dim3(256), dim3(1024), 0, stream>>>(x, bvec, m, eps,
      bk_w, bk_b, bv_w, bv_b, hk_b, hv_b,
      mu1_w, mu1_b, sg1_w, sg1_b, mut_b, sgt_b,
      hkp, hvp, mutp, sgtp, Qp4, Vws, (float*)d_out);
}

// Round 8
// 6223.968 us; speedup vs baseline: 1.3912x; 1.3084x over previous
//
#include <hip/hip_runtime.h>
#include <hip/hip_bf16.h>
#include <stdint.h>

// Sizes from the reference
#define BS   256
#define T_   128
#define TP   127      // T-1
#define DD   128
#define DT   16
#define DB   32
#define DH   256
#define NH   4
#define DS   64
#define DHN  1024

#define OFFV (256u*127u*64u)   // 2080768, size of each output tensor

typedef __attribute__((ext_vector_type(8))) short short8v;
typedef __attribute__((ext_vector_type(4))) float f32x4;
typedef __attribute__((ext_vector_type(2))) float f32x2;

__device__ __forceinline__ float bf16u(unsigned short u){ return __uint_as_float((unsigned)u << 16); }
__device__ __forceinline__ float bf16lo(unsigned u){ return __uint_as_float(u << 16); }
__device__ __forceinline__ float bf16hi(unsigned u){ return __uint_as_float(u & 0xffff0000u); }
__device__ __forceinline__ unsigned short f2bf(float f){
  unsigned u = __float_as_uint(f);
  u += 0x7fffu + ((u >> 16) & 1u);   // RNE
  return (unsigned short)(u >> 16);
}
__device__ __forceinline__ unsigned pk2(float lo, float hi){
  return (unsigned)f2bf(lo) | ((unsigned)f2bf(hi) << 16);
}
__device__ __forceinline__ float softplus_f(float x){
  return fmaxf(x, 0.f) + log1pf(__expf(-fabsf(x)));
}
__device__ __forceinline__ unsigned pk4fp8(float f0, float f1, float f2, float f3){
  int pk8 = __builtin_amdgcn_cvt_pk_fp8_f32(f0, f1, 0, false);
  pk8     = __builtin_amdgcn_cvt_pk_fp8_f32(f2, f3, pk8, true);
  return (unsigned)pk8;
}

#define REP32(M) M(0) M(1) M(2) M(3) M(4) M(5) M(6) M(7) M(8) M(9) M(10) M(11) \
  M(12) M(13) M(14) M(15) M(16) M(17) M(18) M(19) M(20) M(21) M(22) M(23) \
  M(24) M(25) M(26) M(27) M(28) M(29) M(30) M(31)
#define REP8(M) M(0) M(1) M(2) M(3) M(4) M(5) M(6) M(7)

// ---------------------------------------------------------------------------
// Kernel 1: pack recurrent weights to bf16, paired along the reduction dim.
// ---------------------------------------------------------------------------
__global__ __launch_bounds__(256) void pack_w_kernel(
    const float* __restrict__ hk_w, const float* __restrict__ hv_w,
    const float* __restrict__ mut_w, const float* __restrict__ sgt_w,
    unsigned* __restrict__ hkp, unsigned* __restrict__ hvp,
    unsigned* __restrict__ mutp, unsigned* __restrict__ sgtp)
{
  int i = blockIdx.x * 256 + threadIdx.x;
  if (i < 32*256) { int s2 = i >> 8, d = i & 255;
    hkp[i] = pk2(hk_w[(2*s2)*256 + d], hk_w[(2*s2+1)*256 + d]); }
  if (i < 32*1024) { int s2 = i >> 10, j = i & 1023;
    hvp[i] = pk2(hv_w[(2*s2)*1024 + j], hv_w[(2*s2+1)*1024 + j]); }
  if (i < 512*64) { int J2 = i >> 6, k = i & 63;
    mutp[i] = pk2(mut_w[(2*J2)*64 + k], mut_w[(2*J2+1)*64 + k]);
    sgtp[i] = pk2(sgt_w[(2*J2)*64 + k], sgt_w[(2*J2+1)*64 + k]); }
}

// ---------------------------------------------------------------------------
// Kernel 2: projection GEMM (MFMA bf16 16x16x32).  One block per b.
// Outputs DIRECTLY in fp8:
//   Qf8[b][r=t*4+h][d4]  (dword = 4 consecutive d)   -> streamed by recur
//   Vf8[b][n][j]         (dword = t=4n..4n+3, col j) -> LDS-staged by recur
// ---------------------------------------------------------------------------
#define LDA 168

__global__ __launch_bounds__(256) void proj_kernel(
    const float* __restrict__ x, const float* __restrict__ a,
    const float* __restrict__ q_w, const float* __restrict__ q_b,
    const float* __restrict__ v_w, const float* __restrict__ v_b,
    unsigned* __restrict__ Qf8, unsigned* __restrict__ Vf8)
{
  const int b    = blockIdx.x;
  const int tid  = threadIdx.x;
  const int lane = tid & 63;
  const int w    = tid >> 6;

  __shared__ __align__(16) unsigned short A_s[128 * LDA];
  __shared__ __align__(16) unsigned short BC_s[64 * LDA];

  for (int idx = tid; idx < 128 * DD; idx += 256) {
    int t = idx >> 7, k = idx & 127;
    float v = (t < TP) ? x[((size_t)b * T_ + 1 + t) * DD + k] : 0.f;
    A_s[t * LDA + k] = f2bf(v);
  }
  for (int idx = tid; idx < 128 * 40; idx += 256) {
    int t = idx / 40, kk = idx % 40;
    float v = (t < TP && kk < DT) ? a[((size_t)b * T_ + t) * DT + kk] : 0.f;
    A_s[t * LDA + 128 + kk] = f2bf(v);
  }
  __syncthreads();

  for (int nt = 0; nt < 32; ++nt) {
    const int n0 = nt * 64;
    const bool isQ = (n0 < DHN);
    const float* wsrc = isQ ? q_w : v_w;
    const float* bias = isQ ? q_b : v_b;
    const int nb = isQ ? n0 : (n0 - DHN);

    for (int idx = tid; idx < 160 * 64; idx += 256) {
      int k = idx >> 6, n = idx & 63;
      float v = (k < DD + DT) ? wsrc[(size_t)k * DHN + nb + n] : 0.f;
      BC_s[n * LDA + k] = f2bf(v);
    }
    __syncthreads();

    f32x4 acc[2][4];
#pragma unroll
    for (int mi = 0; mi < 2; ++mi)
#pragma unroll
      for (int ni = 0; ni < 4; ++ni) { f32x4 zz = {0.f,0.f,0.f,0.f}; acc[mi][ni] = zz; }
    const int mb = w * 32;
#pragma unroll
    for (int kc = 0; kc < 5; ++kc) {
      const int ko = kc * 32 + ((lane >> 4) << 3);
      short8v af[2], bf[4];
#pragma unroll
      for (int mi = 0; mi < 2; ++mi)
        af[mi] = *(const short8v*)&A_s[(mb + mi*16 + (lane & 15)) * LDA + ko];
#pragma unroll
      for (int ni = 0; ni < 4; ++ni)
        bf[ni] = *(const short8v*)&BC_s[(ni*16 + (lane & 15)) * LDA + ko];
#pragma unroll
      for (int mi = 0; mi < 2; ++mi)
#pragma unroll
        for (int ni = 0; ni < 4; ++ni)
          acc[mi][ni] = __builtin_amdgcn_mfma_f32_16x16x32_bf16(af[mi], bf[ni], acc[mi][ni], 0, 0, 0);
    }
    __syncthreads();

#pragma unroll
    for (int mi = 0; mi < 2; ++mi)
#pragma unroll
      for (int ni = 0; ni < 4; ++ni) {
        int cl = ni*16 + (lane & 15);
        float bb = bias[nb + cl];
#pragma unroll
        for (int q = 0; q < 4; ++q) {
          int t = mb + mi*16 + ((lane >> 4) << 2) + q;
          float vv = acc[mi][ni][q] + bb;
          if (isQ) vv = fmaxf(vv, 0.f);
          BC_s[t * 66 + cl] = f2bf(vv);
        }
      }
    __syncthreads();

    if (isQ) {
      // Qf8[b][r][d4global], d4global = (n0>>4) + d4l, d4l=0..3
      for (int idx = tid; idx < 4 * 512; idx += 256) {
        int d4l = idx >> 9, r = idx & 511;
        int t = r >> 2, h = r & 3;
        const unsigned short* cr = &BC_s[t * 66 + d4l * 16 + h];
        unsigned pk = pk4fp8(bf16u(cr[0]), bf16u(cr[4]), bf16u(cr[8]), bf16u(cr[12]));
        Qf8[((size_t)b * 512 + r) * 64 + (n0 >> 4) + d4l] = pk;
      }
    } else {
      // Vf8[b][n][j], n = t4 group 0..31, j = (n0-1024) + jl
      int c0v = n0 - DHN;
      for (int idx = tid; idx < 32 * 64; idx += 256) {
        int n = idx >> 6, jl = idx & 63;
        unsigned pk = pk4fp8(bf16u(BC_s[(4*n+0) * 66 + jl]), bf16u(BC_s[(4*n+1) * 66 + jl]),
                             bf16u(BC_s[(4*n+2) * 66 + jl]), bf16u(BC_s[(4*n+3) * 66 + jl]));
        Vf8[((size_t)b * 32 + n) * 1024 + c0v + jl] = pk;
      }
    }
    __syncthreads();
  }
}

// ---------------------------------------------------------------------------
// Kernel 3: 127-step recurrence.  One block per b, 1024 threads (16 waves).
// NO large per-thread register state (R2-R7 all spilled it to scratch):
//   V fp8 lives in 128 KB DYNAMIC LDS (PV reads conflict-free);
//   Q fp8 streamed from global every step (L1/L2/L3-served, 128 KB/blk/step).
// ---------------------------------------------------------------------------
__global__ __launch_bounds__(1024, 1)
void recur_kernel(
    const float* __restrict__ x, const float* __restrict__ bvec,
    const float* __restrict__ m, const float* __restrict__ eps,
    const float* __restrict__ bk_w, const float* __restrict__ bk_b,
    const float* __restrict__ bv_w, const float* __restrict__ bv_b,
    const float* __restrict__ hk_b, const float* __restrict__ hv_b,
    const float* __restrict__ mu1_w, const float* __restrict__ mu1_b,
    const float* __restrict__ sg1_w, const float* __restrict__ sg1_b,
    const float* __restrict__ mut_b, const float* __restrict__ sgt_b,
    const unsigned* __restrict__ hkp, const unsigned* __restrict__ hvp,
    const unsigned* __restrict__ mutp, const unsigned* __restrict__ sgtp,
    const unsigned* __restrict__ Qf8, const unsigned* __restrict__ Vf8,
    float* __restrict__ out)
{
  const int b    = blockIdx.x;
  const int tid  = threadIdx.x;
  const int lane = tid & 63;
  const int wvid = tid >> 6;          // 0..15

  extern __shared__ __align__(16) unsigned ldsV[];   // [32][1024] fp8 dwords = 128 KB

  __shared__ __align__(16) float key_s[DH];
  __shared__ __align__(16) float sc[1024];       // partial scores [dhalf][r]
  __shared__ __align__(16) float p_T[4][128];    // p transposed [h][t]
  __shared__ __align__(16) float ht_s[DHN];
  __shared__ __align__(16) float red[16 * 64];   // [sel*8+g][k]
  __shared__ __align__(16) float z_s[DS];
  __shared__ __align__(16) float xb[DD + DB];
  __shared__ float mask_s[128];
  __shared__ __align__(16) float hkb_s[DH];
  __shared__ __align__(16) float hvb_s[DHN];
  __shared__ float mtb_s[DS], stb_s[DS];

  // ---- preload small constants ----
  if (tid < DD + DB) xb[tid] = (tid < DD) ? x[(size_t)b * T_ * DD + tid] : bvec[b * DB + (tid - DD)];
  if (tid >= 256 && tid < 512) hkb_s[tid - 256] = hk_b[tid - 256];
  hvb_s[tid] = hv_b[tid];
  if (tid < DS) { mtb_s[tid] = mut_b[tid]; stb_s[tid] = sgt_b[tid]; }
  if (tid < 512) ((float*)p_T)[tid] = 0.f;   // p_T[h][127] stays 0 forever

  // ---- stage V fp8 into LDS (one-time, coalesced) ----
  {
    const unsigned* vp = Vf8 + (size_t)b * 32 * 1024 + tid;
#pragma unroll
    for (int n = 0; n < 32; ++n) ldsV[n * 1024 + tid] = vp[n * 1024];
  }

  // ---- mask[t] ----
  for (int t = wvid; t < TP; t += 16) {
    const float* mr = m + ((size_t)b * T_ + 1 + t) * DD;
    float s = mr[lane] + mr[lane + 64];
    for (int o = 1; o < 64; o <<= 1) s += __shfl_xor(s, o);
    if (lane == 0) mask_s[t] = (s > 0.f) ? 1.f : 0.f;
  }
  __syncthreads();

  const int r     = tid & 511;        // score row (t*4+h)
  const int dhalf = tid >> 9;         // 0 or 1: which 128-d half
  const int hW    = tid >> 8;         // head for PV (uniform per wave)
  const uint4* qrow = (const uint4*)(Qf8 + ((size_t)b * 512 + r) * 64 + dhalf * 32);
  const float* kb_base = &key_s[dhalf * 128];

  float myval = 0.f;                  // val column owned by this thread

  // ================= unified steps 0..126 =================
  for (int st = 0; st < TP; ++st) {
    // ---------- key (tid<256) / val (all threads, kept in register) ----------
    if (st == 0) {
      float av = bv_b[tid];
      for (int s = 0; s < DD + DB; ++s) av = fmaf(xb[s], bv_w[(size_t)s * DHN + tid], av);
      myval = av;
      if (tid < 256) {
        float ak = bk_b[tid];
        for (int s = 0; s < DD + DB; ++s) ak = fmaf(xb[s], bk_w[s * DH + tid], ak);
        key_s[tid] = fmaxf(ak, 0.f);
      }
    } else {
      float av = hvb_s[tid];
#pragma unroll 8
      for (int s2 = 0; s2 < 32; ++s2) {
        float2 zz = *(const float2*)&z_s[s2 * 2];
        unsigned w0 = hvp[s2 * 1024 + tid];
        av = fmaf(zz.x, bf16lo(w0), av); av = fmaf(zz.y, bf16hi(w0), av);
      }
      myval = av;
      if (tid < 256) {
        float ak = hkb_s[tid];
#pragma unroll 8
        for (int s2 = 0; s2 < 32; ++s2) {
          float2 zz = *(const float2*)&z_s[s2 * 2];
          unsigned wq = hkp[s2 * 256 + tid];
          ak = fmaf(zz.x, bf16lo(wq), ak); ak = fmaf(zz.y, bf16hi(wq), ak);
        }
        key_s[tid] = fmaxf(ak, 0.f);
      }
    }
    __syncthreads();

    // ---------- half-scores: row r, d in [dhalf*128, dhalf*128+128) ----------
    {
      float acc = 0.f;
#define SCD(wrd, koff) { f32x2 a01 = __builtin_amdgcn_cvt_pk_f32_fp8((wrd), false); \
      f32x2 a23 = __builtin_amdgcn_cvt_pk_f32_fp8((wrd), true); \
      float4 kk = *(const float4*)&kb_base[(koff)]; \
      acc = fmaf(a01.x, kk.x, acc); acc = fmaf(a01.y, kk.y, acc); \
      acc = fmaf(a23.x, kk.z, acc); acc = fmaf(a23.y, kk.w, acc); }
#define SCCH(c) { uint4 qc = qrow[c]; \
      SCD(qc.x, (c)*16 + 0) SCD(qc.y, (c)*16 + 4) SCD(qc.z, (c)*16 + 8) SCD(qc.w, (c)*16 + 12) }
      REP8(SCCH)
#undef SCCH
#undef SCD
      sc[tid] = acc;    // raw partial; scale+mask applied in softmax
    }
    __syncthreads();

    // ---------- softmax over t, per head h = wave 0..3 (tid<256) ----------
    if (tid < 256) {
      int h = wvid, l = lane;
      int i1 = l * 4 + h;
      float v1 = (mask_s[l] > 0.f) ? (sc[i1] + sc[512 + i1]) * 0.0625f : -1e9f;
      float v2 = -3.0e38f;
      if (l + 64 < TP) {
        int i2 = (l + 64) * 4 + h;
        v2 = (mask_s[l + 64] > 0.f) ? (sc[i2] + sc[512 + i2]) * 0.0625f : -1e9f;
      }
      float mm = fmaxf(v1, v2);
      for (int o = 1; o < 64; o <<= 1) mm = fmaxf(mm, __shfl_xor(mm, o));
      float e1 = __expf(v1 - mm);
      float e2 = (l + 64 < TP) ? __expf(v2 - mm) : 0.f;
      float ssum = e1 + e2;
      for (int o = 1; o < 64; o <<= 1) ssum += __shfl_xor(ssum, o);
      float inv = 1.f / ssum;
      p_T[h][l] = e1 * inv;
      if (l + 64 < TP) p_T[h][l + 64] = e2 * inv;
    }
    __syncthreads();

    // ---------- PV: thread owns col j=tid; V from LDS (conflict-free) ----------
    {
      float a = 0.f;
#define PVD(n) { unsigned wv8 = ldsV[(n) * 1024 + tid]; \
      float4 pp = *(const float4*)&p_T[hW][4 * (n)]; \
      f32x2 v01 = __builtin_amdgcn_cvt_pk_f32_fp8(wv8, false); \
      f32x2 v23 = __builtin_amdgcn_cvt_pk_f32_fp8(wv8, true); \
      a = fmaf(pp.x, v01.x, a); a = fmaf(pp.y, v01.y, a); \
      a = fmaf(pp.z, v23.x, a); a = fmaf(pp.w, v23.y, a); }
      REP32(PVD)
#undef PVD
      ht_s[tid] = fmaxf(0.5f * (a + myval), 0.f);
    }
    __syncthreads();

    // ---------- mu/sg matvec: k=tid&63, sel=(tid>>6)&1, g=tid>>7 ----------
    {
      int k = tid & 63, sel = (tid >> 6) & 1, g = tid >> 7;
      float acc;
      if (st == 0) {
        const float* wsel = sel ? sg1_w : mu1_w;
        acc = 0.f;
        for (int jl = g * 128; jl < g * 128 + 128; ++jl)
          acc = fmaf(ht_s[jl], wsel[(size_t)jl * 64 + k], acc);
      } else {
        const unsigned* wp = sel ? sgtp : mutp;
        float a0 = 0.f, a1 = 0.f;
#pragma unroll 4
        for (int j2 = g * 64; j2 < g * 64 + 64; ++j2) {
          float2 hh = *(const float2*)&ht_s[j2 * 2];
          unsigned wm = wp[j2 * 64 + k];
          a0 = fmaf(hh.x, bf16lo(wm), a0);
          a1 = fmaf(hh.y, bf16hi(wm), a1);
        }
        acc = a0 + a1;
      }
      red[(sel * 8 + g) * 64 + k] = acc;
    }
    __syncthreads();

    if (tid < 64) {
      float mu = (st == 0) ? mu1_b[tid] : mtb_s[tid];
      float sl = (st == 0) ? sg1_b[tid] : stb_s[tid];
#pragma unroll
      for (int g = 0; g < 8; ++g) { mu += red[g * 64 + tid]; sl += red[(8 + g) * 64 + tid]; }
      float sg = softplus_f(sl);
      float z  = fmaf(sg, eps[((size_t)st * BS + b) * 64 + tid], mu);
      size_t o0 = ((size_t)b * TP + st) * 64 + tid;
      out[o0] = z; out[OFFV + o0] = mu; out[2ull * OFFV + o0] = sg;
      z_s[tid] = z;
    }
    __syncthreads();
  }
}

// ---------------------------------------------------------------------------
extern "C" void kernel_launch(void* const* d_in, const int* in_sizes, int n_in,
                              void* d_out, int out_size, void* d_ws, size_t ws_size,
                              hipStream_t stream) {
  const float* x    = (const float*)d_in[0];
  const float* a    = (const float*)d_in[1];
  const float* m    = (const float*)d_in[2];
  const float* bvec = (const float*)d_in[3];
  const float* eps  = (const float*)d_in[4];
  const float* bk_w = (const float*)d_in[5];
  const float* bk_b = (const float*)d_in[6];
  const float* bv_w = (const float*)d_in[7];
  const float* bv_b = (const float*)d_in[8];
  const float* q_w  = (const float*)d_in[9];
  const float* q_b  = (const float*)d_in[10];
  const float* v_w  = (const float*)d_in[11];
  const float* v_b  = (const float*)d_in[12];
  const float* hk_w = (const float*)d_in[13];
  const float* hk_b = (const float*)d_in[14];
  const float* hv_w = (const float*)d_in[15];
  const float* hv_b = (const float*)d_in[16];
  const float* mu1_w= (const float*)d_in[17];
  const float* mu1_b= (const float*)d_in[18];
  const float* sg1_w= (const float*)d_in[19];
  const float* sg1_b= (const float*)d_in[20];
  const float* mut_w= (const float*)d_in[21];
  const float* mut_b= (const float*)d_in[22];
  const float* sgt_w= (const float*)d_in[23];
  const float* sgt_b= (const float*)d_in[24];

  // workspace: Qf8 32MB | Vf8 32MB | packed weights ~416KB
  char* ws = (char*)d_ws;
  unsigned* Qf8  = (unsigned*)ws;
  unsigned* Vf8  = (unsigned*)(ws + (32ull << 20));
  unsigned* hkp  = (unsigned*)(ws + (64ull << 20));
  unsigned* hvp  = hkp + 32 * 256;
  unsigned* mutp = hvp + 32 * 1024;
  unsigned* sgtp = mutp + 512 * 64;

  pack_w_kernel<<<dim3(128), dim3(256), 0, stream>>>(hk_w, hv_w, mut_w, sgt_w,
                                                     hkp, hvp, mutp, sgtp);
  proj_kernel<<<dim3(256), dim3(256), 0, stream>>>(x, a, q_w, q_b, v_w, v_b, Qf8, Vf8);
  recur_kernel<<<dim3(256), dim3(1024), 131072, stream>>>(x, bvec, m, eps,
      bk_w, bk_b, bv_w, bv_b, hk_b, hv_b,
      mu1_w, mu1_b, sg1_w, sg1_b, mut_b, sgt_b,
      hkp, hvp, mutp, sgtp, Qf8, Vf8, (float*)d_out);
}